// Round 1
// baseline (7050.130 us; speedup 1.0000x reference)
//
#include <hip/hip_runtime.h>

typedef float f4 __attribute__((ext_vector_type(4)));

#define NBLK   512
#define BT     64
#define NT     320
#define SEQN   12
#define HIDP   320

// ws offsets in floats
#define OFF_PART   0          // [512][2][96]
#define OFF_SCALE  98304      // [96]
#define OFF_SHIFT  98400      // [96]
#define OFF_W4     98496      // [320][320][4]  W4[k][j][t] = W_hh[t*300+j][k], zero-padded
#define OFF_WIH4   508096     // [8][320][4]    Wih4[i][j][t] = W_ih[t*300+j][i]
#define OFF_B4     518336     // [320][4]       b_ih + b_hh, padded 0
#define OFF_A2     519616     // [12][320][16]  A2[s][k][u] = W_ta[u][s*300+k] (u<12), W_out[k] (u==12)
#define WS_FLOATS  581056

#define SMEM_FLOATS 35080
#define SMEM_BYTES  (SMEM_FLOATS * 4)

__device__ __forceinline__ float sigm_(float v) { return 1.f / (1.f + __expf(-v)); }
__device__ __forceinline__ float tanh_(float v) { float e = __expf(2.f * v); return 1.f - 2.f / (e + 1.f); }

// ---------------- Kernel 1: BN partial sums (deterministic) ----------------
__global__ __launch_bounds__(192) void bn_partial_k(const float* __restrict__ x,
                                                    float* __restrict__ ws) {
    __shared__ float sm[2][2][96];
    int t = threadIdx.x;
    int half = t / 96, f = t - half * 96;   // t < 192
    int r0 = blockIdx.x * 64 + half * 32;
    float s1 = 0.f, s2 = 0.f;
    for (int r = 0; r < 32; ++r) {
        float v = x[(size_t)(r0 + r) * 96 + f];
        s1 += v; s2 += v * v;
    }
    sm[half][0][f] = s1; sm[half][1][f] = s2;
    __syncthreads();
    if (t < 96) {
        ws[OFF_PART + blockIdx.x * 192 + t]      = sm[0][0][t] + sm[1][0][t];
        ws[OFF_PART + blockIdx.x * 192 + 96 + t] = sm[0][1][t] + sm[1][1][t];
    }
}

// ---------------- Kernel 2: finalize BN + build tables ----------------
__global__ __launch_bounds__(256) void prep_k(const float* __restrict__ bn_gamma,
                                              const float* __restrict__ bn_beta,
                                              const float* __restrict__ W_ih,
                                              const float* __restrict__ b_ih,
                                              const float* __restrict__ W_hh,
                                              const float* __restrict__ b_hh,
                                              const float* __restrict__ W_ta,
                                              const float* __restrict__ W_out,
                                              float* __restrict__ ws) {
    int idx = blockIdx.x * 256 + threadIdx.x;
    if (idx < 409600) {   // W4
        int k = idx / 1280; int rem = idx - k * 1280; int j = rem >> 2; int t = rem & 3;
        float v = 0.f;
        if (k < 300 && j < 300) v = W_hh[(size_t)(t * 300 + j) * 300 + k];
        ws[OFF_W4 + idx] = v; return;
    }
    int i2 = idx - 409600;
    if (i2 < 10240) {     // Wih4
        int i = i2 / 1280; int rem = i2 - i * 1280; int j = rem >> 2; int t = rem & 3;
        float v = 0.f;
        if (j < 300) v = W_ih[(size_t)(t * 300 + j) * 8 + i];
        ws[OFF_WIH4 + i2] = v; return;
    }
    int i3 = i2 - 10240;
    if (i3 < 1280) {      // bias
        int j = i3 >> 2; int t = i3 & 3;
        float v = 0.f;
        if (j < 300) v = b_ih[t * 300 + j] + b_hh[t * 300 + j];
        ws[OFF_B4 + i3] = v; return;
    }
    int i4 = i3 - 1280;
    if (i4 < 61440) {     // A2
        int s = i4 / 5120; int rem = i4 - s * 5120; int k = rem >> 4; int u = rem & 15;
        float v = 0.f;
        if (k < 300) {
            if (u < 12)       v = W_ta[(size_t)u * 3600 + s * 300 + k];
            else if (u == 12) v = W_out[k];
        }
        ws[OFF_A2 + i4] = v; return;
    }
    int i5 = i4 - 61440;
    if (i5 < 96) {        // finalize scale/shift
        float s1 = 0.f, s2 = 0.f;
        for (int b = 0; b < 512; ++b) {
            s1 += ws[OFF_PART + b * 192 + i5];
            s2 += ws[OFF_PART + b * 192 + 96 + i5];
        }
        float mu  = s1 * (1.f / 32768.f);
        float var = s2 * (1.f / 32768.f) - mu * mu;
        float rs  = rsqrtf(var + 1e-5f);
        float sc  = bn_gamma[i5] * rs;
        ws[OFF_SCALE + i5] = sc;
        ws[OFF_SHIFT + i5] = bn_beta[i5] - mu * sc;
    }
}

// ---------------- Kernel 3: fused BN-apply + proj + attn + LSTM + out ----------------
__global__ __launch_bounds__(NT) void mega_k(const float* __restrict__ x,
                                             const float* __restrict__ W_in,
                                             const float* __restrict__ W_sa,
                                             const float* __restrict__ b_sa,
                                             const float* __restrict__ b_ta,
                                             const float* __restrict__ ws,
                                             float* __restrict__ out) {
    extern __shared__ float sm[];
    float* h_lds = sm;                    // [320][68]
    float* xg    = sm + 21760;            // [64][96]
    float* A2s   = sm + 27904;            // [320][16]
    float* ta    = sm + 33024;            // [64][16]
    float* qv    = sm + 34048;            // [64][12]
    float* scs   = sm + 34816;            // [96]
    float* shs   = sm + 34912;            // [96]
    float* wsa   = sm + 35008;            // [8][8]
    float* bsa   = sm + 35072;            // [8]

    const int tid = threadIdx.x;
    const int gr0 = blockIdx.x * BT;
    const float* gW4  = ws + OFF_W4;
    const float* gWih = ws + OFF_WIH4;
    const float* gB4  = ws + OFF_B4;
    const float* gA2  = ws + OFF_A2;

    // ---- phase 1: BN apply + input projection + spatial attention ----
    float* Win = h_lds;            // [96][97] overlay (h zeroed later)
    float* xn  = h_lds + 9312;     // [64][96]

    for (int i = tid; i < 96; i += NT) { scs[i] = ws[OFF_SCALE + i]; shs[i] = ws[OFF_SHIFT + i]; }
    for (int i = tid; i < 64; i += NT) wsa[i] = W_sa[i];
    for (int i = tid; i < 8;  i += NT) bsa[i] = b_sa[i];
    for (int i = tid; i < 96 * 96; i += NT) { int r = i / 96, c = i - r * 96; Win[r * 97 + c] = W_in[i]; }
    __syncthreads();
    for (int i = tid; i < BT * 96; i += NT) {
        int c = i % 96;
        xn[i] = x[(size_t)gr0 * 96 + i] * scs[c] + shs[c];
    }
    __syncthreads();
    for (int i = tid; i < BT * 96; i += NT) {      // y = xn @ W_in^T
        int row = i / 96, col = i - row * 96;
        const float* xr = xn + row * 96;
        const float* wr = Win + col * 97;
        float acc = 0.f;
        #pragma unroll 8
        for (int jj = 0; jj < 96; ++jj) acc += xr[jj] * wr[jj];
        xg[i] = acc;
    }
    __syncthreads();
    for (int p = tid; p < BT * SEQN; p += NT) {    // spatial attention, in-place
        int row = p / 12, s = p - row * 12;
        float* yv = xg + row * 96 + s * 8;
        float y[8], e[8];
        #pragma unroll
        for (int jj = 0; jj < 8; ++jj) y[jj] = yv[jj];
        float mx = -1e30f;
        #pragma unroll
        for (int jj = 0; jj < 8; ++jj) {
            float a = bsa[jj];
            #pragma unroll
            for (int ii = 0; ii < 8; ++ii) a += y[ii] * wsa[jj * 8 + ii];
            a = sigm_(a);
            e[jj] = a; mx = fmaxf(mx, a);
        }
        float den = 0.f;
        #pragma unroll
        for (int jj = 0; jj < 8; ++jj) { e[jj] = __expf(e[jj] - mx); den += e[jj]; }
        float inv = 1.f / den;
        #pragma unroll
        for (int jj = 0; jj < 8; ++jj) yv[jj] = y[jj] * e[jj] * inv;
    }
    for (int i = tid; i < 320 * 68; i += NT) h_lds[i] = 0.f;       // zero h (overwrites Win/xn)
    for (int p = tid; p < BT * 16; p += NT) { int u = p & 15; ta[p] = (u < 12) ? b_ta[u] : 0.f; }
    __syncthreads();

    // ---- phase 2: LSTM ----
    const int j = tid;                         // gate column 0..319 (>=300 padded -> h stays 0)
    f4 bb = *reinterpret_cast<const f4*>(gB4 + j * 4);
    float cS[64];
    #pragma unroll
    for (int r = 0; r < 64; ++r) cS[r] = 0.f;

    #pragma unroll 1
    for (int s = 0; s < SEQN; ++s) {
        for (int i = tid; i < 320 * 16; i += NT) A2s[i] = gA2[s * 5120 + i];   // attn slab

        #pragma unroll
        for (int p = 0; p < 8; ++p) {
            const int r0 = p * 8;
            float acc[4][8];
            #pragma unroll
            for (int t = 0; t < 4; ++t)
                #pragma unroll
                for (int r = 0; r < 8; ++r) acc[t][r] = bb[t];
            // input-gate contribution (xg broadcast across all lanes)
            #pragma unroll
            for (int ii = 0; ii < 8; ++ii) {
                f4 wih = *reinterpret_cast<const f4*>(gWih + (ii * 320 + j) * 4);
                #pragma unroll
                for (int r = 0; r < 8; ++r) {
                    float xv = xg[(r0 + r) * 96 + s * 8 + ii];
                    acc[0][r] += wih[0] * xv; acc[1][r] += wih[1] * xv;
                    acc[2][r] += wih[2] * xv; acc[3][r] += wih[3] * xv;
                }
            }
            // recurrent matmul: k over full hidden vector
            #pragma unroll 4
            for (int k = 0; k < HIDP; ++k) {
                f4 w  = *reinterpret_cast<const f4*>(gW4 + ((size_t)k * 320 + j) * 4);
                f4 ha = *reinterpret_cast<const f4*>(&h_lds[k * 68 + r0]);
                f4 hb = *reinterpret_cast<const f4*>(&h_lds[k * 68 + r0 + 4]);
                #pragma unroll
                for (int r = 0; r < 4; ++r) {
                    acc[0][r]     += w[0] * ha[r]; acc[1][r]     += w[1] * ha[r];
                    acc[2][r]     += w[2] * ha[r]; acc[3][r]     += w[3] * ha[r];
                    acc[0][r + 4] += w[0] * hb[r]; acc[1][r + 4] += w[1] * hb[r];
                    acc[2][r + 4] += w[2] * hb[r]; acc[3][r + 4] += w[3] * hb[r];
                }
            }
            __syncthreads();   // all reads of row-octet p done before overwrite
            #pragma unroll
            for (int r = 0; r < 8; ++r) {
                float ig = sigm_(acc[0][r]);
                float fg = sigm_(acc[1][r]);
                float gg = tanh_(acc[2][r]);
                float og = sigm_(acc[3][r]);
                float cn = fg * cS[r0 + r] + ig * gg;
                cS[r0 + r] = cn;
                h_lds[j * 68 + (r0 + r)] = og * tanh_(cn);
            }
        }
        __syncthreads();
        // temporal-attention logit + q accumulation
        for (int pp = tid; pp < BT * 16; pp += NT) {
            int row = pp >> 4, u = pp & 15;
            if (u < 13) {
                float acc = 0.f;
                for (int k = 0; k < 300; ++k) acc += h_lds[k * 68 + row] * A2s[k * 16 + u];
                if (u < 12) ta[pp] += acc;
                else        qv[row * 12 + s] = acc;
            }
        }
        __syncthreads();
    }

    // ---- phase 3: softmax(relu(ta)) and output ----
    if (tid < BT) {
        float l[12]; float mx = 0.f;
        #pragma unroll
        for (int s2 = 0; s2 < 12; ++s2) {
            float v = fmaxf(ta[tid * 16 + s2], 0.f);
            l[s2] = v; mx = fmaxf(mx, v);
        }
        float den = 0.f, o = 0.f;
        #pragma unroll
        for (int s2 = 0; s2 < 12; ++s2) {
            float e = __expf(l[s2] - mx);
            den += e; o += e * qv[tid * 12 + s2];
        }
        out[gr0 + tid] = o / den;
    }
}

extern "C" void kernel_launch(void* const* d_in, const int* in_sizes, int n_in,
                              void* d_out, int out_size, void* d_ws, size_t ws_size,
                              hipStream_t stream) {
    const float* x        = (const float*)d_in[0];
    const float* bn_gamma = (const float*)d_in[1];
    const float* bn_beta  = (const float*)d_in[2];
    const float* W_in     = (const float*)d_in[3];
    const float* W_sa     = (const float*)d_in[4];
    const float* b_sa     = (const float*)d_in[5];
    const float* W_ih     = (const float*)d_in[6];
    const float* b_ih     = (const float*)d_in[7];
    const float* W_hh     = (const float*)d_in[8];
    const float* b_hh     = (const float*)d_in[9];
    const float* W_ta     = (const float*)d_in[10];
    const float* b_ta     = (const float*)d_in[11];
    const float* W_out    = (const float*)d_in[12];
    float* ws  = (float*)d_ws;
    float* out = (float*)d_out;

    (void)in_sizes; (void)n_in; (void)out_size; (void)ws_size;

    // allow >64KB dynamic LDS (ignore result; harmless if unnecessary)
    (void)hipFuncSetAttribute((const void*)mega_k,
                              hipFuncAttributeMaxDynamicSharedMemorySize, SMEM_BYTES);

    bn_partial_k<<<NBLK, 192, 0, stream>>>(x, ws);
    prep_k<<<1886, 256, 0, stream>>>(bn_gamma, bn_beta, W_ih, b_ih, W_hh, b_hh, W_ta, W_out, ws);
    mega_k<<<NBLK, NT, SMEM_BYTES, stream>>>(x, W_in, W_sa, b_sa, b_ta, ws, out);
}

// Round 2
// 1675.185 us; speedup vs baseline: 4.2086x; 4.2086x over previous
//
#include <hip/hip_runtime.h>

typedef float  f32x4  __attribute__((ext_vector_type(4)));
typedef short  short8 __attribute__((ext_vector_type(8)));
typedef unsigned int uint;
typedef unsigned short ushort;

#define NT    512
#define SEQN  12

// ws offsets (in 4-byte units)
#define OFF_PART   0          // [512][2][96] BN partials
#define OFF_SCALE  98304      // [96]
#define OFF_SHIFT  98400      // [96]
#define OFF_WG     98496      // 409600 u32: [kt10][half2][tile40][lane64][8u32: 4 hi-pairs, 4 lo-pairs]
#define OFF_WA     508096     // 66560 u32:  [s13][kt10][lane64][8u32]

#define WG_U32     409600
#define WA_U32     66560

#define SMEM_BYTES 113696

__device__ __forceinline__ float sigm_(float v) { return 1.f / (1.f + __expf(-v)); }
__device__ __forceinline__ float tanh_(float v) { float e = __expf(2.f * v); return 1.f - 2.f / (e + 1.f); }

// f32 -> bf16 (round to nearest even), returns low 16 bits
__device__ __forceinline__ uint f2b(float v) {
    uint u = __float_as_uint(v);
    return (u + 0x7FFFu + ((u >> 16) & 1u)) >> 16;
}
__device__ __forceinline__ float b2f(uint b) { return __uint_as_float(b << 16); }
// swizzled byte offset into h arrays ([64][320] ushort)
__device__ __forceinline__ int haddr(int row, int u) {
    return ((row * 640 + u * 2) ^ ((row & 7) << 4));
}

// ---------------- Kernel 1: BN partial sums ----------------
__global__ __launch_bounds__(192) void bn_partial_k(const float* __restrict__ x,
                                                    float* __restrict__ ws) {
    __shared__ float sm[2][2][96];
    int t = threadIdx.x;
    int half = t / 96, f = t - half * 96;
    int r0 = blockIdx.x * 64 + half * 32;
    float s1 = 0.f, s2 = 0.f;
    for (int r = 0; r < 32; ++r) {
        float v = x[(size_t)(r0 + r) * 96 + f];
        s1 += v; s2 += v * v;
    }
    sm[half][0][f] = s1; sm[half][1][f] = s2;
    __syncthreads();
    if (t < 96) {
        ws[OFF_PART + blockIdx.x * 192 + t]      = sm[0][0][t] + sm[1][0][t];
        ws[OFF_PART + blockIdx.x * 192 + 96 + t] = sm[0][1][t] + sm[1][1][t];
    }
}

// ---------------- Kernel 2: build bf16-split fragment tables ----------------
__device__ __forceinline__ float wg_val(int kt, int half, int tile, int lane, int e,
                                        const float* W_hh, const float* W_ih,
                                        const float* b_ih, const float* b_hh) {
    int u = half * 160 + (tile % 10) * 16 + (lane & 15);
    int g = tile / 10;
    int k = kt * 32 + ((lane >> 4) << 3) + e;
    if (u >= 300) return 0.f;
    int gu = g * 300 + u;
    if (k < 300)  return W_hh[(size_t)gu * 300 + k];
    if (k == 300) return b_ih[gu] + b_hh[gu];
    if (k >= 312) return W_ih[gu * 8 + (k - 312)];
    return 0.f;
}
__device__ __forceinline__ float wa_val(int s, int kt, int lane, int e,
                                        const float* W_ta, const float* W_out) {
    if (s == 0) return 0.f;
    int u = lane & 15;
    int k = kt * 32 + ((lane >> 4) << 3) + e;
    if (k >= 300 || u > 12) return 0.f;
    if (u < 12) return W_ta[(size_t)u * 3600 + (s - 1) * 300 + k];
    return W_out[k];
}

__global__ __launch_bounds__(256) void prep_k(const float* __restrict__ bn_gamma,
                                              const float* __restrict__ bn_beta,
                                              const float* __restrict__ W_ih,
                                              const float* __restrict__ b_ih,
                                              const float* __restrict__ W_hh,
                                              const float* __restrict__ b_hh,
                                              const float* __restrict__ W_ta,
                                              const float* __restrict__ W_out,
                                              float* __restrict__ ws) {
    int idx = blockIdx.x * 256 + threadIdx.x;
    uint* wsu = (uint*)ws;
    if (idx < WG_U32) {
        int word = idx & 7;  int entry = idx >> 3;
        int lane = entry & 63; int e2 = entry >> 6;
        int tile = e2 % 40;  int e3 = e2 / 40;
        int half = e3 & 1;   int kt = e3 >> 1;
        int e0 = (word & 3) * 2; int isLo = word >> 2;
        float v0 = wg_val(kt, half, tile, lane, e0,     W_hh, W_ih, b_ih, b_hh);
        float v1 = wg_val(kt, half, tile, lane, e0 + 1, W_hh, W_ih, b_ih, b_hh);
        uint h0 = f2b(v0), l0 = f2b(v0 - b2f(h0));
        uint h1 = f2b(v1), l1 = f2b(v1 - b2f(h1));
        uint b0 = isLo ? l0 : h0, b1 = isLo ? l1 : h1;
        wsu[OFF_WG + idx] = b0 | (b1 << 16);
        return;
    }
    int i2 = idx - WG_U32;
    if (i2 < WA_U32) {
        int word = i2 & 7;  int entry = i2 >> 3;
        int lane = entry & 63; int e2 = entry >> 6;
        int kt = e2 % 10;   int s = e2 / 10;
        int e0 = (word & 3) * 2; int isLo = word >> 2;
        float v0 = wa_val(s, kt, lane, e0,     W_ta, W_out);
        float v1 = wa_val(s, kt, lane, e0 + 1, W_ta, W_out);
        uint h0 = f2b(v0), l0 = f2b(v0 - b2f(h0));
        uint h1 = f2b(v1), l1 = f2b(v1 - b2f(h1));
        uint b0 = isLo ? l0 : h0, b1 = isLo ? l1 : h1;
        wsu[OFF_WA + i2] = b0 | (b1 << 16);
        return;
    }
    int i5 = i2 - WA_U32;
    if (i5 < 96) {
        float s1 = 0.f, s2 = 0.f;
        for (int b = 0; b < 512; ++b) {
            s1 += ws[OFF_PART + b * 192 + i5];
            s2 += ws[OFF_PART + b * 192 + 96 + i5];
        }
        float mu  = s1 * (1.f / 32768.f);
        float var = s2 * (1.f / 32768.f) - mu * mu;
        float rs  = rsqrtf(var + 1e-5f);
        float sc  = bn_gamma[i5] * rs;
        ws[OFF_SCALE + i5] = sc;
        ws[OFF_SHIFT + i5] = bn_beta[i5] - mu * sc;
    }
}

// ---------------- Kernel 3: fused everything ----------------
__global__ __launch_bounds__(NT, 2) void mega_k(const float* __restrict__ x,
                                                const float* __restrict__ W_in,
                                                const float* __restrict__ W_sa,
                                                const float* __restrict__ b_sa,
                                                const float* __restrict__ b_ta,
                                                const float* __restrict__ ws,
                                                float* __restrict__ out) {
    extern __shared__ char smc[];
    ushort* h_hi  = (ushort*)smc;                 // [64][320] bf16 hi, swizzled
    ushort* h_lo  = (ushort*)(smc + 40960);       // [64][320] bf16 lo, swizzled
    float*  xg    = (float*)(smc + 81920);        // [64][96]
    float*  q_lds = (float*)(smc + 106496);       // [64][12]
    float*  ta_l  = (float*)(smc + 109568);       // [64][12]
    float*  scs   = (float*)(smc + 112640);       // [96]
    float*  shs   = (float*)(smc + 113024);       // [96]
    float*  wsa   = (float*)(smc + 113408);       // [8][8]
    float*  bsa   = (float*)(smc + 113664);       // [8]
    float*  Win   = (float*)smc;                  // phase-1 overlay [96][97]
    float*  xn    = (float*)(smc + 37248);        // phase-1 overlay [64][96]

    const int tid = threadIdx.x;
    const int gr0 = blockIdx.x * 64;

    // ---- phase 1: BN apply + input projection + spatial attention ----
    for (int i = tid; i < 96; i += NT) { scs[i] = ws[OFF_SCALE + i]; shs[i] = ws[OFF_SHIFT + i]; }
    for (int i = tid; i < 64; i += NT) wsa[i] = W_sa[i];
    for (int i = tid; i < 8;  i += NT) bsa[i] = b_sa[i];
    for (int i = tid; i < 96 * 96; i += NT) { int r = i / 96, c = i - r * 96; Win[r * 97 + c] = W_in[i]; }
    __syncthreads();
    for (int i = tid; i < 64 * 96; i += NT) {
        int c = i % 96;
        xn[i] = x[(size_t)gr0 * 96 + i] * scs[c] + shs[c];
    }
    __syncthreads();
    for (int i = tid; i < 64 * 96; i += NT) {
        int row = i / 96, col = i - row * 96;
        const float* xr = xn + row * 96;
        const float* wr = Win + col * 97;
        float acc = 0.f;
        #pragma unroll 8
        for (int jj = 0; jj < 96; ++jj) acc += xr[jj] * wr[jj];
        xg[i] = acc;
    }
    __syncthreads();
    for (int p = tid; p < 64 * SEQN; p += NT) {
        int row = p / 12, s = p - row * 12;
        float* yv = xg + row * 96 + s * 8;
        float y[8], e[8];
        #pragma unroll
        for (int jj = 0; jj < 8; ++jj) y[jj] = yv[jj];
        float mx = -1e30f;
        #pragma unroll
        for (int jj = 0; jj < 8; ++jj) {
            float a = bsa[jj];
            #pragma unroll
            for (int ii = 0; ii < 8; ++ii) a += y[ii] * wsa[jj * 8 + ii];
            a = sigm_(a);
            e[jj] = a; mx = fmaxf(mx, a);
        }
        float den = 0.f;
        #pragma unroll
        for (int jj = 0; jj < 8; ++jj) { e[jj] = __expf(e[jj] - mx); den += e[jj]; }
        float inv = 1.f / den;
        #pragma unroll
        for (int jj = 0; jj < 8; ++jj) yv[jj] = y[jj] * e[jj] * inv;
    }
    __syncthreads();
    // zero h arrays (also retires phase-1 overlays)
    for (int i = tid; i < 64 * 320; i += NT) { h_hi[i] = 0; h_lo[i] = 0; }
    __syncthreads();
    // bias slot (unit 300 == 1.0) + xg slots for step 0 (units 312..319)
    for (int r = tid; r < 64; r += NT)
        *(ushort*)((char*)h_hi + haddr(r, 300)) = 0x3F80;
    {
        int row = tid >> 3, e = tid & 7;
        float v = xg[row * 96 + e];
        uint hb = f2b(v), lb = f2b(v - b2f(hb));
        *(ushort*)((char*)h_hi + haddr(row, 312 + e)) = (ushort)hb;
        *(ushort*)((char*)h_lo + haddr(row, 312 + e)) = (ushort)lb;
    }
    __syncthreads();

    // ---- phase 2: LSTM via split-bf16 MFMA ----
    const int wv   = tid >> 6, lane = tid & 63;
    const int mt   = wv >> 1,  half = wv & 1;
    const int rb   = mt * 16;
    const int arow = rb + (lane & 15);              // A-fragment row
    const int drow0= rb + ((lane >> 4) << 2);       // D rows base
    const int lcol = lane & 15;
    const char* wg_b = (const char*)(ws + OFF_WG);
    const char* wa_b = (const char*)(ws + OFF_WA);

    f32x4 acc[40];
    f32x4 accA = {0.f, 0.f, 0.f, 0.f};
    float cst[40];
    #pragma unroll
    for (int t = 0; t < 40; ++t) cst[t] = 0.f;

    #pragma unroll 1
    for (int s = 0; s < SEQN; ++s) {
        #pragma unroll
        for (int t = 0; t < 40; ++t) acc[t] = (f32x4){0.f, 0.f, 0.f, 0.f};

        #pragma unroll 1
        for (int kt = 0; kt < 10; ++kt) {
            const int koff = kt * 32 + ((lane >> 4) << 3);
            short8 ahi = *(const short8*)((const char*)h_hi + haddr(arow, koff));
            short8 alo = *(const short8*)((const char*)h_lo + haddr(arow, koff));
            const char* bp = wg_b + ((size_t)(((kt * 2 + half) * 40) * 64 + lane)) * 32;
            #pragma unroll
            for (int t = 0; t < 40; ++t) {
                short8 bhi = *(const short8*)(bp);
                short8 blo = *(const short8*)(bp + 16);
                bp += 2048;
                acc[t] = __builtin_amdgcn_mfma_f32_16x16x32_bf16(ahi, bhi, acc[t], 0, 0, 0);
                acc[t] = __builtin_amdgcn_mfma_f32_16x16x32_bf16(ahi, blo, acc[t], 0, 0, 0);
                acc[t] = __builtin_amdgcn_mfma_f32_16x16x32_bf16(alo, bhi, acc[t], 0, 0, 0);
            }
            if (half) {
                const char* ap = wa_b + ((size_t)((s * 10 + kt) * 64 + lane)) * 32;
                short8 bhi = *(const short8*)(ap);
                short8 blo = *(const short8*)(ap + 16);
                accA = __builtin_amdgcn_mfma_f32_16x16x32_bf16(ahi, bhi, accA, 0, 0, 0);
                accA = __builtin_amdgcn_mfma_f32_16x16x32_bf16(ahi, blo, accA, 0, 0, 0);
                accA = __builtin_amdgcn_mfma_f32_16x16x32_bf16(alo, bhi, accA, 0, 0, 0);
            }
        }
        __syncthreads();   // all h reads for this step complete

        // activation + h write (gate g lives at acc[g*10+usub], same lane/reg)
        #pragma unroll
        for (int us = 0; us < 10; ++us) {
            int u = half * 160 + us * 16 + lcol;
            bool live = (u < 300);
            #pragma unroll
            for (int r = 0; r < 4; ++r) {
                float iv = sigm_(acc[0 * 10 + us][r]);
                float fv = sigm_(acc[1 * 10 + us][r]);
                float gv = tanh_(acc[2 * 10 + us][r]);
                float ov = sigm_(acc[3 * 10 + us][r]);
                float cn = fv * cst[us * 4 + r] + iv * gv;
                cst[us * 4 + r] = cn;
                float hv = ov * tanh_(cn);
                if (live) {
                    int row = drow0 + r;
                    uint hb = f2b(hv), lb = f2b(hv - b2f(hb));
                    *(ushort*)((char*)h_hi + haddr(row, u)) = (ushort)hb;
                    *(ushort*)((char*)h_lo + haddr(row, u)) = (ushort)lb;
                }
            }
        }
        // q extraction (col 12 of attention tile) + reset
        if (half && lcol == 12) {
            #pragma unroll
            for (int r = 0; r < 4; ++r) {
                if (s >= 1) q_lds[(drow0 + r) * 12 + (s - 1)] = accA[r];
                accA[r] = 0.f;
            }
        }
        // xg slots for next step
        if (s < SEQN - 1) {
            int row = tid >> 3, e = tid & 7;
            float v = xg[row * 96 + (s + 1) * 8 + e];
            uint hb = f2b(v), lb = f2b(v - b2f(hb));
            *(ushort*)((char*)h_hi + haddr(row, 312 + e)) = (ushort)hb;
            *(ushort*)((char*)h_lo + haddr(row, 312 + e)) = (ushort)lb;
        }
        __syncthreads();
    }

    // ---- final attention pass for h_11 ----
    if (half) {
        #pragma unroll 1
        for (int kt = 0; kt < 10; ++kt) {
            const int koff = kt * 32 + ((lane >> 4) << 3);
            short8 ahi = *(const short8*)((const char*)h_hi + haddr(arow, koff));
            short8 alo = *(const short8*)((const char*)h_lo + haddr(arow, koff));
            const char* ap = wa_b + ((size_t)((12 * 10 + kt) * 64 + lane)) * 32;
            short8 bhi = *(const short8*)(ap);
            short8 blo = *(const short8*)(ap + 16);
            accA = __builtin_amdgcn_mfma_f32_16x16x32_bf16(ahi, bhi, accA, 0, 0, 0);
            accA = __builtin_amdgcn_mfma_f32_16x16x32_bf16(ahi, blo, accA, 0, 0, 0);
            accA = __builtin_amdgcn_mfma_f32_16x16x32_bf16(alo, bhi, accA, 0, 0, 0);
        }
        if (lcol < 12) {
            #pragma unroll
            for (int r = 0; r < 4; ++r) ta_l[(drow0 + r) * 12 + lcol] = accA[r];
        } else if (lcol == 12) {
            #pragma unroll
            for (int r = 0; r < 4; ++r) q_lds[(drow0 + r) * 12 + 11] = accA[r];
        }
    }
    __syncthreads();

    // ---- phase 3: softmax(relu(ta + b_ta)) and output ----
    if (tid < 64) {
        float l[12]; float mx = 0.f;
        #pragma unroll
        for (int s2 = 0; s2 < 12; ++s2) {
            float v = fmaxf(ta_l[tid * 12 + s2] + b_ta[s2], 0.f);
            l[s2] = v; mx = fmaxf(mx, v);
        }
        float den = 0.f, o = 0.f;
        #pragma unroll
        for (int s2 = 0; s2 < 12; ++s2) {
            float e = __expf(l[s2] - mx);
            den += e; o += e * q_lds[tid * 12 + s2];
        }
        out[gr0 + tid] = o / den;
    }
}

extern "C" void kernel_launch(void* const* d_in, const int* in_sizes, int n_in,
                              void* d_out, int out_size, void* d_ws, size_t ws_size,
                              hipStream_t stream) {
    const float* x        = (const float*)d_in[0];
    const float* bn_gamma = (const float*)d_in[1];
    const float* bn_beta  = (const float*)d_in[2];
    const float* W_in     = (const float*)d_in[3];
    const float* W_sa     = (const float*)d_in[4];
    const float* b_sa     = (const float*)d_in[5];
    const float* W_ih     = (const float*)d_in[6];
    const float* b_ih     = (const float*)d_in[7];
    const float* W_hh     = (const float*)d_in[8];
    const float* b_hh     = (const float*)d_in[9];
    const float* W_ta     = (const float*)d_in[10];
    const float* b_ta     = (const float*)d_in[11];
    const float* W_out    = (const float*)d_in[12];
    float* ws  = (float*)d_ws;
    float* out = (float*)d_out;

    (void)in_sizes; (void)n_in; (void)out_size; (void)ws_size;

    (void)hipFuncSetAttribute((const void*)mega_k,
                              hipFuncAttributeMaxDynamicSharedMemorySize, SMEM_BYTES);

    bn_partial_k<<<512, 192, 0, stream>>>(x, ws);
    int prep_items = WG_U32 + WA_U32 + 96;
    prep_k<<<(prep_items + 255) / 256, 256, 0, stream>>>(bn_gamma, bn_beta, W_ih, b_ih,
                                                         W_hh, b_hh, W_ta, W_out, ws);
    mega_k<<<512, NT, SMEM_BYTES, stream>>>(x, W_in, W_sa, b_sa, b_ta, ws, out);
}